// Round 2
// baseline (342.317 us; speedup 1.0000x reference)
//
#include <hip/hip_runtime.h>
#include <stdint.h>

// Problem: B=4,Q=75,C=5 -> 1500 groups; D=512; P=36. fp32 in/out.
// Round-6 theory: global_load_lds DMA has tiny per-CU concurrency (~3-4 KB
// in flight -> ~9 GB/s/CU from HBM; round-1 measured 20.3us/block for 147KB).
// Fix: stage global->VGPR->LDS with plain dwordx4 loads (vmcnt MLP, 147KB
// truly in flight), persistent blocks (256 x ~6 groups) with a register
// double-buffer: next group's 18 float4/thread load during current group's
// compute. Single global touch preserved; compute hidden under load.
#define NGRP 1500
#define DD   512
#define PP   36
#define DP   (DD*PP)          // 18432 floats per tensor per group
#define NB   256              // persistent blocks (1 per CU)
#define NT   512              // threads per block (8 waves)
#define QPT  9                // float4 per tensor per thread (9*16B*512 = 73728B)
#define SCALE_CLS 7.0f
#define EPS 1e-12f

__device__ __forceinline__ float waveRed(float x){
  #pragma unroll
  for (int off = 32; off; off >>= 1) x += __shfl_xor(x, off, 64);
  return x;
}

// no __restrict__: may-alias 'out' stores make rematerialization of the
// prefetched loads illegal -> the 72 staging VGPRs must stay live.
__global__ __launch_bounds__(NT, 2)
void topk_fuse(const float* gtrain, const float* gtest,
               const int* Kp, float* out)
{
  __shared__ float sT[DP];                 // test  [512][36]
  __shared__ float sR[DP];                 // train [512][36]
  __shared__ float s_tm[DD], s_rm[DD];     // row (d) means
  __shared__ float s_q[PP], s_e[PP];       // per-pos sumsq (test/train)
  __shared__ float s_a[PP], s_b[PP];       // per-pos dots with other mean
  __shared__ float s_nt[PP], s_nr[PP];     // per-pos norms
  __shared__ float s_st[PP], s_sr[PP];     // ranking scores
  __shared__ __align__(16) float s_wt[PP]; // fuse weights test
  __shared__ __align__(16) float s_wr[PP]; // fuse weights train
  __shared__ float s_red[24];

  const int t    = threadIdx.x;
  const int lane = t & 63;
  const int wave = t >> 6;                 // 0..7
  const int b    = blockIdx.x;
  const int K    = Kp[0];
  const int nj   = (NGRP - b + NB - 1) / NB;   // 6 (b<220) or 5

  // ---- Prologue: load group b into registers (18 x dwordx4, coalesced). ----
  float4 pT[QPT], pR[QPT];
  {
    const float4* gT4 = (const float4*)(gtest  + (size_t)b * DP);
    const float4* gR4 = (const float4*)(gtrain + (size_t)b * DP);
    #pragma unroll
    for (int s = 0; s < QPT; ++s) pT[s] = gT4[t + NT*s];
    #pragma unroll
    for (int s = 0; s < QPT; ++s) pR[s] = gR4[t + NT*s];
  }
  if (t < PP) { s_q[t] = 0.f; s_e[t] = 0.f; s_a[t] = 0.f; s_b[t] = 0.f; }

  for (int j = 0; j < nj; ++j) {
    const int g = b + NB * j;

    // ---- Stage regs -> LDS (WAR on pT/pR keeps this before the prefetch).
    float4* sT4 = (float4*)sT;
    float4* sR4 = (float4*)sR;
    #pragma unroll
    for (int s = 0; s < QPT; ++s) sT4[t + NT*s] = pT[s];
    #pragma unroll
    for (int s = 0; s < QPT; ++s) sR4[t + NT*s] = pR[s];

    // ---- Prefetch next group into the freed registers (in flight across
    //      the whole compute phase; block-uniform branch).
    if (j + 1 < nj) {
      const int g2 = g + NB;
      const float4* gT4 = (const float4*)(gtest  + (size_t)g2 * DP);
      const float4* gR4 = (const float4*)(gtrain + (size_t)g2 * DP);
      #pragma unroll
      for (int s = 0; s < QPT; ++s) pT[s] = gT4[t + NT*s];
      #pragma unroll
      for (int s = 0; s < QPT; ++s) pR[s] = gR4[t + NT*s];
    }
    __builtin_amdgcn_sched_barrier(0);   // don't sink the prefetch into compute
    __syncthreads();                                              // A: staged

    // ---- Row means (both tensors) + mean-cosine partials. ----
    const float4* rt4 = (const float4*)(sT + t * PP);
    const float4* rr4 = (const float4*)(sR + t * PP);
    float st = 0.f, sr = 0.f;
    #pragma unroll
    for (int i = 0; i < 9; ++i) {
      float4 x = rt4[i], y = rr4[i];
      st += (x.x + x.y) + (x.z + x.w);
      sr += (y.x + y.y) + (y.z + y.w);
    }
    const float tm = st * (1.0f/36.0f), rm = sr * (1.0f/36.0f);
    s_tm[t] = tm; s_rm[t] = rm;
    {
      float pm2 = waveRed(tm * tm);
      float pr2 = waveRed(rm * rm);
      float pmr = waveRed(tm * rm);
      if (lane == 0) { s_red[wave] = pm2; s_red[8+wave] = pr2; s_red[16+wave] = pmr; }
    }
    __syncthreads();                                              // B

    if (t == 0) {
      float m2 = 0.f, r2 = 0.f, mr = 0.f;
      #pragma unroll
      for (int w = 0; w < 8; ++w) { m2 += s_red[w]; r2 += s_red[8+w]; mr += s_red[16+w]; }
      out[g] = SCALE_CLS * mr / (fmaxf(sqrtf(m2), EPS) * fmaxf(sqrtf(r2), EPS));
    }

    // ---- Column pass: q,e (sumsq) and a,b (dots with other mean). ----
    if (t < 504) {
      const int p = t % 36, c = t / 36;    // 14 d-chunks x 36 positions
      float q = 0.f, e = 0.f, a = 0.f, bb = 0.f;
      for (int d = c; d < DD; d += 14) {
        const int i = d * PP + p;
        float x = sT[i], y = sR[i];
        q += x * x;        e += y * y;
        a += x * s_rm[d];  bb += y * s_tm[d];
      }
      atomicAdd(&s_q[p], q);  atomicAdd(&s_e[p], e);
      atomicAdd(&s_a[p], a);  atomicAdd(&s_b[p], bb);
    }
    __syncthreads();                                              // C

    // ---- Norms + ranking scores (positive group factors dropped). ----
    if (wave < 2 && lane < PP) {
      const float* qq = wave ? s_e : s_q;
      const float* dm = wave ? s_b : s_a;
      float n  = fmaxf(sqrtf(qq[lane]), EPS);
      float sc = dm[lane] / n;
      if (wave) { s_nr[lane] = n; s_sr[lane] = sc; }
      else      { s_nt[lane] = n; s_st[lane] = sc; }
    }
    __syncthreads();                                              // D

    // ---- Top-K via ranks (jnp ties: lower index wins) -> fuse weights. ----
    if (wave < 2 && lane < PP) {
      const float* sc = wave ? s_sr : s_st;
      const float* nn = wave ? s_nr : s_nt;
      float*       w  = wave ? s_wr : s_wt;
      float mine = sc[lane];
      int rank = 0;
      #pragma unroll
      for (int p = 0; p < PP; ++p) {
        float o = sc[p];
        rank += ((o > mine) || (o == mine && p < lane)) ? 1 : 0;
      }
      w[lane] = (rank < K) ? (1.0f / nn[lane]) : 0.f;
    }
    // re-zero accumulators for the next group (idle wave, post-last-read)
    if (wave == 2 && lane < PP) { s_q[lane]=0.f; s_e[lane]=0.f; s_a[lane]=0.f; s_b[lane]=0.f; }
    __syncthreads();                                              // E

    // ---- Fuse: weighted row sums (1/K cancels in l2norm) + cosine. ----
    {
      const float4* w4t = (const float4*)s_wt;
      const float4* w4r = (const float4*)s_wr;
      float U = 0.f, V = 0.f;
      #pragma unroll
      for (int i = 0; i < 9; ++i) {
        float4 x = rt4[i], y = rr4[i], wa = w4t[i], wb = w4r[i];
        U += x.x*wa.x + x.y*wa.y + x.z*wa.z + x.w*wa.w;
        V += y.x*wb.x + y.y*wb.y + y.z*wb.z + y.w*wb.w;
      }
      float u2 = waveRed(U * U);
      float v2 = waveRed(V * V);
      float uv = waveRed(U * V);
      if (lane == 0) { s_red[wave] = u2; s_red[8+wave] = v2; s_red[16+wave] = uv; }
    }
    __syncthreads();                                              // F
    if (t == 0) {
      float u2 = 0.f, v2 = 0.f, uv = 0.f;
      #pragma unroll
      for (int w = 0; w < 8; ++w) { u2 += s_red[w]; v2 += s_red[8+w]; uv += s_red[16+w]; }
      out[NGRP + g] = SCALE_CLS * uv / (fmaxf(sqrtf(u2), EPS) * fmaxf(sqrtf(v2), EPS));
    }
    // next iteration's ds_writes are safe: all sT/sR reads precede barrier F,
    // and s_red is next written only after barrier A of iteration j+1.
  }
}

extern "C" void kernel_launch(void* const* d_in, const int* in_sizes, int n_in,
                              void* d_out, int out_size, void* d_ws, size_t ws_size,
                              hipStream_t stream)
{
  const float* ftrain = (const float*)d_in[0];
  const float* ftest  = (const float*)d_in[1];
  const int*   Kp     = (const int*)d_in[2];
  float*       out    = (float*)d_out;
  topk_fuse<<<NB, NT, 0, stream>>>(ftrain, ftest, Kp, out);
}

// Round 3
// 299.411 us; speedup vs baseline: 1.1433x; 1.1433x over previous
//
#include <hip/hip_runtime.h>
#include <stdint.h>

// Problem: B=4,Q=75,C=5 -> 1500 groups; D=512; P=36. fp32 in/out.
// Round-7: round-2's persistent register double-buffer SPILLED (VGPR stayed 88,
// WRITE_SIZE 216 MB scratch). New plan: overlap via TLP, not pipelining.
// 1500 non-persistent blocks; train tensor in LDS (73.7 KB, coalesced staged),
// test tensor register-resident thread-per-row (36 VGPRs, no loop-carried
// liveness). LDS ~78 KB + VGPR<=128 -> 2 blocks/CU: one block loads while the
// other computes. Test-side column sums (q,a) via 2-level shfl + spread atomics.
#define NGRP 1500
#define DD   512
#define PP   36
#define DP   (DD*PP)          // 18432 floats per tensor per group
#define NT   512
#define SCALE_CLS 7.0f
#define EPS 1e-12f

__device__ __forceinline__ float waveRed(float x){
  #pragma unroll
  for (int off = 32; off; off >>= 1) x += __shfl_xor(x, off, 64);
  return x;
}

__global__ __launch_bounds__(NT, 4)   // 4 waves/EU = 16 waves/CU = 2 blocks
void topk_fuse(const float* __restrict__ gtrain,
               const float* __restrict__ gtest,
               const int* __restrict__ Kp,
               float* __restrict__ out)
{
  __shared__ float sR[DP];                 // train [512][36]  (73728 B)
  __shared__ float s_tm[DD];               // test row means (table for b-pass)
  __shared__ float s_q4[4][PP];            // spread accum: test per-pos sumsq
  __shared__ float s_a4[4][PP];            // spread accum: sum T*rm
  __shared__ float s_e[PP], s_b[PP];       // train per-pos sumsq / dot tm
  __shared__ float s_nt[PP], s_nr[PP];     // per-pos norms
  __shared__ float s_st[PP], s_sr[PP];     // ranking scores
  __shared__ __align__(16) float s_wt[PP]; // fuse weights test
  __shared__ __align__(16) float s_wr[PP]; // fuse weights train
  __shared__ float s_red[24];

  const int t    = threadIdx.x;
  const int lane = t & 63;
  const int wave = t >> 6;                 // 0..7
  const int g    = blockIdx.x;
  const int K    = Kp[0];

  // ---- Loads: test row-per-thread (kept in regs), train coalesced (to LDS).
  float4 rowT[9];                          // 36 VGPRs, live to the end
  {
    const float4* gTrow = (const float4*)(gtest + (size_t)g * DP + (size_t)t * PP);
    #pragma unroll
    for (int i = 0; i < 9; ++i) rowT[i] = gTrow[i];
  }
  {
    const float4* gR4 = (const float4*)(gtrain + (size_t)g * DP);
    float4 r0=gR4[t],        r1=gR4[t+NT],   r2=gR4[t+2*NT], r3=gR4[t+3*NT],
           r4=gR4[t+4*NT],   r5=gR4[t+5*NT], r6=gR4[t+6*NT], r7=gR4[t+7*NT],
           r8=gR4[t+8*NT];
    float4* sR4 = (float4*)sR;
    sR4[t]      = r0; sR4[t+NT]   = r1; sR4[t+2*NT] = r2; sR4[t+3*NT] = r3;
    sR4[t+4*NT] = r4; sR4[t+5*NT] = r5; sR4[t+6*NT] = r6; sR4[t+7*NT] = r7;
    sR4[t+8*NT] = r8;
  }

  if (t < PP) {
    s_e[t] = 0.f; s_b[t] = 0.f;
    #pragma unroll
    for (int v = 0; v < 4; ++v) { s_q4[v][t] = 0.f; s_a4[v][t] = 0.f; }
  }

  // ---- Test row mean from registers; publish table for the b column-pass.
  float acc = 0.f;
  #pragma unroll
  for (int i = 0; i < 9; ++i) { float4 x = rowT[i]; acc += (x.x + x.y) + (x.z + x.w); }
  const float tm = acc * (1.0f / 36.0f);
  s_tm[t] = tm;

  __syncthreads();                                              // A: sR, s_tm, zeros

  // ---- Train row mean from own LDS row. ----
  const float4* rr4 = (const float4*)(sR + t * PP);
  float accr = 0.f;
  #pragma unroll
  for (int i = 0; i < 9; ++i) { float4 y = rr4[i]; accr += (y.x + y.y) + (y.z + y.w); }
  const float rm = accr * (1.0f / 36.0f);

  // ---- Mean-cosine partials. ----
  {
    float pm2 = waveRed(tm * tm);
    float pr2 = waveRed(rm * rm);
    float pmr = waveRed(tm * rm);
    if (lane == 0) { s_red[wave] = pm2; s_red[8+wave] = pr2; s_red[16+wave] = pmr; }
  }

  // ---- Test-side column sums q[p], a[p]: 2-level butterfly + spread atomics.
  {
    const int slot = (lane >> 2) & 3;          // 4 lanes per slot-address
    #pragma unroll
    for (int i = 0; i < 9; ++i) {
      float4 x = rowT[i];
      #pragma unroll
      for (int cpt = 0; cpt < 4; ++cpt) {
        const float xv = (cpt == 0) ? x.x : (cpt == 1) ? x.y : (cpt == 2) ? x.z : x.w;
        const int p = 4 * i + cpt;
        float q = xv * xv;
        float a = xv * rm;                     // rm is this thread's own row d=t
        q += __shfl_xor(q, 1, 64); q += __shfl_xor(q, 2, 64);
        a += __shfl_xor(a, 1, 64); a += __shfl_xor(a, 2, 64);
        if ((lane & 3) == 0) {
          atomicAdd(&s_q4[slot][p], q);
          atomicAdd(&s_a4[slot][p], a);
        }
      }
    }
  }

  // ---- Train-side column pass: e[p], b[p] (needs s_tm). ----
  if (t < 504) {
    const int p = t % 36, c = t / 36;          // 14 d-chunks x 36 positions
    float e = 0.f, bb = 0.f;
    for (int d = c; d < DD; d += 14) {
      float y = sR[d * PP + p];
      e  += y * y;
      bb += y * s_tm[d];
    }
    atomicAdd(&s_e[p], e); atomicAdd(&s_b[p], bb);
  }
  __syncthreads();                                              // B

  // ---- Mean-cosine score (global scores). ----
  if (t == 0) {
    float m2 = 0.f, r2 = 0.f, mr = 0.f;
    #pragma unroll
    for (int w = 0; w < 8; ++w) { m2 += s_red[w]; r2 += s_red[8+w]; mr += s_red[16+w]; }
    out[g] = SCALE_CLS * mr / (fmaxf(sqrtf(m2), EPS) * fmaxf(sqrtf(r2), EPS));
  }

  // ---- Norms + ranking scores (positive group factors dropped). ----
  if (wave < 2 && lane < PP) {
    float q, dm;
    if (wave) { q = s_e[lane]; dm = s_b[lane]; }
    else {
      q  = s_q4[0][lane] + s_q4[1][lane] + s_q4[2][lane] + s_q4[3][lane];
      dm = s_a4[0][lane] + s_a4[1][lane] + s_a4[2][lane] + s_a4[3][lane];
    }
    float n  = fmaxf(sqrtf(q), EPS);
    float sc = dm / n;
    if (wave) { s_nr[lane] = n; s_sr[lane] = sc; }
    else      { s_nt[lane] = n; s_st[lane] = sc; }
  }
  __syncthreads();                                              // C

  // ---- Top-K via ranks (jnp ties: lower index wins) -> fuse weights. ----
  if (wave < 2 && lane < PP) {
    const float* sc = wave ? s_sr : s_st;
    const float* nn = wave ? s_nr : s_nt;
    float*       w  = wave ? s_wr : s_wt;
    float mine = sc[lane];
    int rank = 0;
    #pragma unroll
    for (int p = 0; p < PP; ++p) {
      float o = sc[p];
      rank += ((o > mine) || (o == mine && p < lane)) ? 1 : 0;
    }
    w[lane] = (rank < K) ? (1.0f / nn[lane]) : 0.f;
  }
  __syncthreads();                                              // D

  // ---- Fuse: U from register row (test), V from own LDS row (train). ----
  {
    const float4* w4t = (const float4*)s_wt;
    const float4* w4r = (const float4*)s_wr;
    float U = 0.f, V = 0.f;
    #pragma unroll
    for (int i = 0; i < 9; ++i) {
      float4 x = rowT[i], wa = w4t[i];
      float4 y = rr4[i],  wb = w4r[i];
      U += x.x*wa.x + x.y*wa.y + x.z*wa.z + x.w*wa.w;
      V += y.x*wb.x + y.y*wb.y + y.z*wb.z + y.w*wb.w;
    }
    float u2 = waveRed(U * U);
    float v2 = waveRed(V * V);
    float uv = waveRed(U * V);
    if (lane == 0) { s_red[wave] = u2; s_red[8+wave] = v2; s_red[16+wave] = uv; }
  }
  __syncthreads();                                              // E
  if (t == 0) {
    float u2 = 0.f, v2 = 0.f, uv = 0.f;
    #pragma unroll
    for (int w = 0; w < 8; ++w) { u2 += s_red[w]; v2 += s_red[8+w]; uv += s_red[16+w]; }
    out[NGRP + g] = SCALE_CLS * uv / (fmaxf(sqrtf(u2), EPS) * fmaxf(sqrtf(v2), EPS));
  }
}

extern "C" void kernel_launch(void* const* d_in, const int* in_sizes, int n_in,
                              void* d_out, int out_size, void* d_ws, size_t ws_size,
                              hipStream_t stream)
{
  const float* ftrain = (const float*)d_in[0];
  const float* ftest  = (const float*)d_in[1];
  const int*   Kp     = (const int*)d_in[2];
  float*       out    = (float*)d_out;
  topk_fuse<<<NGRP, NT, 0, stream>>>(ftrain, ftest, Kp, out);
}

// Round 4
// 258.256 us; speedup vs baseline: 1.3255x; 1.1594x over previous
//
#include <hip/hip_runtime.h>
#include <stdint.h>

// Round-8: algebraic restructure. S = [T|R]^T [T|R] (72x72 Gram, symmetric)
// yields ALL outputs: q/e = diag, a/b = G-quadrant row/col sums, m2/r2/mr =
// quadrant sums, u2/v2/uv = quadratic forms with topk weight vectors.
// One streaming pass (K-chunks of 64 rows -> LDS -> rank-64 Gram update on
// register 4x4 tiles), tiny epilogue. No data residency, no multi-pass.
#define NGRP 1500
#define DD   512
#define PP   36
#define MW   72               // combined width [T|R]
#define DP   (DD*PP)          // 18432 floats per tensor per group
#define KC   64               // k-rows per chunk
#define NCH  (DD/KC)          // 8
#define NT   192              // 3 waves
#define NTILE 171             // 18x18 upper-triangle 4x4 tiles over 72x72
#define F4C  (KC*PP/4)        // 576 float4 per tensor per chunk
#define SCALE_CLS 7.0f
#define EPS 1e-12f

__device__ __forceinline__ float waveRed(float x){
  #pragma unroll
  for (int off = 32; off; off >>= 1) x += __shfl_xor(x, off, 64);
  return x;
}

__global__ __launch_bounds__(NT, 4)
void topk_fuse(const float* __restrict__ gtrain,
               const float* __restrict__ gtest,
               const int* __restrict__ Kp,
               float* __restrict__ out)
{
  __shared__ __align__(16) float sM[KC][MW];     // 18432 B chunk buffer
  __shared__ float s_q[PP], s_e[PP];             // Gram diagonals
  __shared__ float s_a[PP], s_b[PP];             // G row / col sums (atomic)
  __shared__ float s_nt[PP], s_nr[PP];           // per-pos norms
  __shared__ float s_st[PP], s_sr[PP];           // ranking scores
  __shared__ __align__(16) float s_x[MW];        // [wt | 0]
  __shared__ __align__(16) float s_y[MW];        // [0 | wr]
  __shared__ float s_sums[3];                    // sum(GT), sum(G), sum(GR)
  __shared__ float s_uvw[3];                     // u2, v2, uv

  const int t    = threadIdx.x;
  const int lane = t & 63;
  const int wave = t >> 6;            // 0..2
  const int g    = blockIdx.x;
  const int K    = Kp[0];

  // ---- triangle tile coords: tile t -> (I,J), I<=J, 18x18 grid ----
  int I = 0;
  { int rem = (t < NTILE) ? t : 0;
    if (t < NTILE) { while (rem >= 18 - I) { rem -= 18 - I; ++I; } }
    else rem = 0;
    // J computed below from I+rem
    (void)rem;
  }
  int J;
  { int rem = t; int ii = 0;
    if (t < NTILE) { while (rem >= 18 - ii) { rem -= 18 - ii; ++ii; } J = ii + rem; I = ii; }
    else { I = 0; J = 0; }
  }

  if (t < PP) { s_a[t] = 0.f; s_b[t] = 0.f; }
  if (t < 3)  { s_sums[t] = 0.f; s_uvw[t] = 0.f; }

  const float4* gT4 = (const float4*)(gtest  + (size_t)g * DP);
  const float4* gR4 = (const float4*)(gtrain + (size_t)g * DP);

  // per-thread LDS write slots (fixed across chunks): f = t, t+NT, t+2NT
  float* wT0 = &sM[(t        )/9][((t        )%9)*4];
  float* wT1 = &sM[(t +   NT )/9][((t +   NT )%9)*4];
  float* wT2 = &sM[(t + 2*NT )/9][((t + 2*NT )%9)*4];

  float acc[4][4] = {{0.f}};

  // ---- prologue: load chunk 0 ----
  float4 vT0 = gT4[t], vT1 = gT4[t+NT], vT2 = gT4[t+2*NT];
  float4 vR0 = gR4[t], vR1 = gR4[t+NT], vR2 = gR4[t+2*NT];

  for (int c = 0; c < NCH; ++c) {
    // ---- stage regs -> LDS (T at col 0, R at col 36) ----
    *(float4*)(wT0)      = vT0; *(float4*)(wT1)      = vT1; *(float4*)(wT2)      = vT2;
    *(float4*)(wT0 + 36) = vR0; *(float4*)(wT1 + 36) = vR1; *(float4*)(wT2 + 36) = vR2;

    // ---- prefetch next chunk (in flight across the Gram compute) ----
    if (c + 1 < NCH) {
      const int nb = (c + 1) * F4C;
      vT0 = gT4[nb+t]; vT1 = gT4[nb+t+NT]; vT2 = gT4[nb+t+2*NT];
      vR0 = gR4[nb+t]; vR1 = gR4[nb+t+NT]; vR2 = gR4[nb+t+2*NT];
    }
    __syncthreads();                                   // chunk staged

    // ---- rank-KC Gram update: acc += M[k][4I..]^T x M[k][4J..] ----
    if (t < NTILE) {
      const float* mI = &sM[0][4*I];
      const float* mJ = &sM[0][4*J];
      #pragma unroll 4
      for (int k = 0; k < KC; ++k) {
        const float4 u = *(const float4*)(mI + k*MW);
        const float4 v = *(const float4*)(mJ + k*MW);
        acc[0][0] += u.x*v.x; acc[0][1] += u.x*v.y; acc[0][2] += u.x*v.z; acc[0][3] += u.x*v.w;
        acc[1][0] += u.y*v.x; acc[1][1] += u.y*v.y; acc[1][2] += u.y*v.z; acc[1][3] += u.y*v.w;
        acc[2][0] += u.z*v.x; acc[2][1] += u.z*v.y; acc[2][2] += u.z*v.z; acc[2][3] += u.z*v.w;
        acc[3][0] += u.w*v.x; acc[3][1] += u.w*v.y; acc[3][2] += u.w*v.z; acc[3][3] += u.w*v.w;
      }
    }
    __syncthreads();                                   // all reads done
  }

  // ---- epilogue 1: tile sums -> quadrant accumulators ----
  if (t < NTILE) {
    float rs0 = acc[0][0]+acc[0][1]+acc[0][2]+acc[0][3];
    float rs1 = acc[1][0]+acc[1][1]+acc[1][2]+acc[1][3];
    float rs2 = acc[2][0]+acc[2][1]+acc[2][2]+acc[2][3];
    float rs3 = acc[3][0]+acc[3][1]+acc[3][2]+acc[3][3];
    float tsum = rs0 + rs1 + rs2 + rs3;
    if (J < 9) {                                       // GT quadrant (I<=J<9)
      atomicAdd(&s_sums[0], (I == J) ? tsum : 2.f * tsum);
    } else if (I >= 9) {                               // GR quadrant
      atomicAdd(&s_sums[2], (I == J) ? tsum : 2.f * tsum);
    } else {                                           // G quadrant (I<9<=J)
      atomicAdd(&s_sums[1], tsum);
      atomicAdd(&s_a[4*I+0], rs0); atomicAdd(&s_a[4*I+1], rs1);
      atomicAdd(&s_a[4*I+2], rs2); atomicAdd(&s_a[4*I+3], rs3);
      #pragma unroll
      for (int cc = 0; cc < 4; ++cc) {
        float cs = acc[0][cc]+acc[1][cc]+acc[2][cc]+acc[3][cc];
        atomicAdd(&s_b[4*(J-9)+cc], cs);
      }
    }
    if (I == J) {                                      // diagonals -> q / e
      if (I < 9) {
        s_q[4*I+0]=acc[0][0]; s_q[4*I+1]=acc[1][1]; s_q[4*I+2]=acc[2][2]; s_q[4*I+3]=acc[3][3];
      } else {
        s_e[4*(I-9)+0]=acc[0][0]; s_e[4*(I-9)+1]=acc[1][1];
        s_e[4*(I-9)+2]=acc[2][2]; s_e[4*(I-9)+3]=acc[3][3];
      }
    }
  }
  __syncthreads();                                     // H

  // ---- global (mean-cosine) score ----
  if (t == 0) {
    float m2 = s_sums[0] * (1.f/1296.f);
    float r2 = s_sums[2] * (1.f/1296.f);
    float mr = s_sums[1] * (1.f/1296.f);
    out[g] = SCALE_CLS * mr / (fmaxf(sqrtf(m2), EPS) * fmaxf(sqrtf(r2), EPS));
  }

  // ---- norms + ranking scores (positive common factors dropped) ----
  if (wave < 2 && lane < PP) {
    float q  = wave ? s_e[lane] : s_q[lane];
    float dm = wave ? s_b[lane] : s_a[lane];
    float n  = fmaxf(sqrtf(q), EPS);
    float sc = dm / n;
    if (wave) { s_nr[lane] = n; s_sr[lane] = sc; }
    else      { s_nt[lane] = n; s_st[lane] = sc; }
  }
  __syncthreads();                                     // I

  // ---- top-K ranks -> padded weight vectors x=[wt|0], y=[0|wr] ----
  if (wave < 2 && lane < PP) {
    const float* sc = wave ? s_sr : s_st;
    const float* nn = wave ? s_nr : s_nt;
    float mine = sc[lane];
    int rank = 0;
    #pragma unroll
    for (int p = 0; p < PP; ++p) {
      float o = sc[p];
      rank += ((o > mine) || (o == mine && p < lane)) ? 1 : 0;
    }
    float w = (rank < K) ? (1.0f / nn[lane]) : 0.f;
    if (wave) s_y[36 + lane] = w;
    else      s_x[lane]      = w;
  }
  if (wave == 2 && lane < PP) { s_x[36 + lane] = 0.f; s_y[lane] = 0.f; }
  __syncthreads();                                     // J

  // ---- quadratic forms: u2 = x'Sx, v2 = y'Sy, uv = x'Sy ----
  float u2 = 0.f, v2 = 0.f, uvv = 0.f;
  if (t < NTILE) {
    float xi[4], xj[4], yi[4], yj[4];
    #pragma unroll
    for (int r = 0; r < 4; ++r) {
      xi[r] = s_x[4*I+r]; xj[r] = s_x[4*J+r];
      yi[r] = s_y[4*I+r]; yj[r] = s_y[4*J+r];
    }
    if (I == J) {
      #pragma unroll
      for (int r = 0; r < 4; ++r)
        #pragma unroll
        for (int cc = 0; cc < 4; ++cc) {
          float A = acc[r][cc];
          u2  += xi[r] * A * xi[cc];
          v2  += yi[r] * A * yi[cc];
          uvv += xi[r] * A * yi[cc];
        }
    } else {
      #pragma unroll
      for (int r = 0; r < 4; ++r)
        #pragma unroll
        for (int cc = 0; cc < 4; ++cc) {
          float A = acc[r][cc];
          u2  += 2.f * xi[r] * A * xj[cc];
          v2  += 2.f * yi[r] * A * yj[cc];
          uvv += xi[r] * A * yj[cc] + yi[r] * A * xj[cc];
        }
    }
  }
  u2  = waveRed(u2);
  v2  = waveRed(v2);
  uvv = waveRed(uvv);
  if (lane == 0) {
    atomicAdd(&s_uvw[0], u2);
    atomicAdd(&s_uvw[1], v2);
    atomicAdd(&s_uvw[2], uvv);
  }
  __syncthreads();                                     // L

  if (t == 0) {
    float nu = fmaxf(sqrtf(s_uvw[0]), EPS);
    float nv = fmaxf(sqrtf(s_uvw[1]), EPS);
    out[NGRP + g] = SCALE_CLS * s_uvw[2] / (nu * nv);
  }
}

extern "C" void kernel_launch(void* const* d_in, const int* in_sizes, int n_in,
                              void* d_out, int out_size, void* d_ws, size_t ws_size,
                              hipStream_t stream)
{
  const float* ftrain = (const float*)d_in[0];
  const float* ftest  = (const float*)d_in[1];
  const int*   Kp     = (const int*)d_in[2];
  float*       out    = (float*)d_out;
  topk_fuse<<<NGRP, NT, 0, stream>>>(ftrain, ftest, Kp, out);
}